// Round 3
// baseline (490.837 us; speedup 1.0000x reference)
//
#include <hip/hip_runtime.h>

// Attention over channel dim: B=16, HW=16384, C=64, fp32.
// scores[b,q,k] = sum_hw Q[b,hw,q]*K[b,hw,k]; attn=softmax_k; out[b,hw,q]=sum_k attn[b,q,k]*V[b,hw,k]
//
// ws layout: partial scores [B][S_SPLIT][64][64] fp32 (8 MB), then attn [B][64][64] fp32 (256 KB).

#define S_SPLIT 32
#define CHUNK (16384 / S_SPLIT)   // 512 rows per split block
#define TILE_ROWS 32              // rows staged in LDS per iteration
#define NTILES (CHUNK / TILE_ROWS)

// ---------------- Kernel A: partial scores (split-K GEMM, 8x8 register tile) ----------------
// 4 waves compute the SAME 64x64 (q,k) tile over disjoint row subsets (r=i*4+w);
// LDS tree reduction combines the 4 quarter-partials before one coalesced store.
// Staging: global_load_lds width=16, double-buffered (loads for t+1 issued before
// compute of t; the vmcnt(0) the compiler emits at the next barrier drains them
// after a full compute phase of overlap).
__global__ __launch_bounds__(256) void scores_kernel(
    const float* __restrict__ Q, const float* __restrict__ K,
    float* __restrict__ partial) {
  const int bs = blockIdx.x;            // b * S_SPLIT + s
  const int b = bs / S_SPLIT;
  const int s = bs % S_SPLIT;
  const int tid = threadIdx.x;
  const int w = tid >> 6;               // wave id 0..3
  const int l = tid & 63;               // lane
  const int q0 = (l >> 3) * 8;          // 8 q per lane
  const int k0 = (l & 7) * 8;           // 8 k per lane

  __shared__ union {
    struct { float4 q[2][512]; float4 k[2][512]; } t;  // 2 x (8KB Q + 8KB K) = 32 KB
    float red[2][4096];                                // 32 KB reduction scratch
  } lds;

  float acc[8][8];
#pragma unroll
  for (int i = 0; i < 8; ++i)
#pragma unroll
    for (int j = 0; j < 8; ++j) acc[i][j] = 0.f;

  const char* Qg = (const char*)(Q + ((size_t)b * 16384 + (size_t)s * CHUNK) * 64);
  const char* Kg = (const char*)(K + ((size_t)b * 16384 + (size_t)s * CHUNK) * 64);

  // stage one 32-row tile (8 KB per matrix) into buffer p via global_load_lds.
  // LDS dest is wave-uniform (w, chunk only); HW adds lane*16.
  auto stage = [&](int t, int p) {
    const char* qsrc = Qg + (size_t)t * 8192;
    const char* ksrc = Kg + (size_t)t * 8192;
    char* qdst = (char*)&lds.t.q[p][0];
    char* kdst = (char*)&lds.t.k[p][0];
#pragma unroll
    for (int c = 0; c < 2; ++c) {
      const int m = w + c * 4;          // 8 chunks of 1024 B per matrix
      __builtin_amdgcn_global_load_lds(
          (const __attribute__((address_space(1))) unsigned*)(qsrc + m * 1024 + l * 16),
          (__attribute__((address_space(3))) unsigned*)(qdst + m * 1024), 16, 0, 0);
      __builtin_amdgcn_global_load_lds(
          (const __attribute__((address_space(1))) unsigned*)(ksrc + m * 1024 + l * 16),
          (__attribute__((address_space(3))) unsigned*)(kdst + m * 1024), 16, 0, 0);
    }
  };

  stage(0, 0);
  for (int t = 0; t < NTILES; ++t) {
    __syncthreads();                    // drains tile-t loads; frees buf (t+1)&1
    if (t + 1 < NTILES) stage(t + 1, (t + 1) & 1);
    const float4* bq = lds.t.q[t & 1];
    const float4* bk = lds.t.k[t & 1];

#pragma unroll
    for (int i = 0; i < 8; ++i) {
      const int r = (i << 2) + w;       // wave w handles rows w,4+w,...,28+w
      float4 qa = bq[r * 16 + (q0 >> 2)];
      float4 qb = bq[r * 16 + (q0 >> 2) + 1];
      float4 ka = bk[r * 16 + (k0 >> 2)];
      float4 kb = bk[r * 16 + (k0 >> 2) + 1];
      float qv[8] = {qa.x, qa.y, qa.z, qa.w, qb.x, qb.y, qb.z, qb.w};
      float kv[8] = {ka.x, ka.y, ka.z, ka.w, kb.x, kb.y, kb.z, kb.w};
#pragma unroll
      for (int ii = 0; ii < 8; ++ii)
#pragma unroll
        for (int jj = 0; jj < 8; ++jj)
          acc[ii][jj] += qv[ii] * kv[jj];
    }
  }

  // ---- cross-wave reduction: waves 2,3 publish; waves 0,1 add; halves summed on store ----
  __syncthreads();                      // all waves done reading tile LDS
  if (w >= 2) {
    float4* dst = (float4*)lds.red[w - 2];
#pragma unroll
    for (int i = 0; i < 8; ++i) {
      dst[(q0 + i) * 16 + (k0 >> 2)]     = make_float4(acc[i][0], acc[i][1], acc[i][2], acc[i][3]);
      dst[(q0 + i) * 16 + (k0 >> 2) + 1] = make_float4(acc[i][4], acc[i][5], acc[i][6], acc[i][7]);
    }
  }
  __syncthreads();
  if (w < 2) {
    float4* dst = (float4*)lds.red[w];
#pragma unroll
    for (int i = 0; i < 8; ++i) {
      float4 u = dst[(q0 + i) * 16 + (k0 >> 2)];
      float4 v = dst[(q0 + i) * 16 + (k0 >> 2) + 1];
      dst[(q0 + i) * 16 + (k0 >> 2)]     = make_float4(u.x + acc[i][0], u.y + acc[i][1], u.z + acc[i][2], u.w + acc[i][3]);
      dst[(q0 + i) * 16 + (k0 >> 2) + 1] = make_float4(v.x + acc[i][4], v.y + acc[i][5], v.z + acc[i][6], v.w + acc[i][7]);
    }
  }
  __syncthreads();
  // cooperative coalesced store of the reduced 64x64 tile
  float4* p4 = (float4*)(partial + (size_t)bs * 4096);
  const float4* r0 = (const float4*)lds.red[0];
  const float4* r1 = (const float4*)lds.red[1];
#pragma unroll
  for (int c = 0; c < 4; ++c) {
    float4 x = r0[c * 256 + tid];
    float4 y = r1[c * 256 + tid];
    p4[c * 256 + tid] = make_float4(x.x + y.x, x.y + y.y, x.z + y.z, x.w + y.w);
  }
}

// ---------------- Kernel B: reduce partials + softmax over k ----------------
__global__ __launch_bounds__(64) void softmax_kernel(
    const float* __restrict__ partial, float* __restrict__ attn) {
  const int bq = blockIdx.x;            // b*64 + q
  const int b = bq >> 6;
  const int q = bq & 63;
  const int k = threadIdx.x;            // lane = k

  float v = 0.f;
  for (int s = 0; s < S_SPLIT; ++s)
    v += partial[((size_t)(b * S_SPLIT + s) * 64 + q) * 64 + k];

  float m = v;
#pragma unroll
  for (int off = 32; off > 0; off >>= 1)
    m = fmaxf(m, __shfl_xor(m, off, 64));
  float e = __expf(v - m);
  float sum = e;
#pragma unroll
  for (int off = 32; off > 0; off >>= 1)
    sum += __shfl_xor(sum, off, 64);
  attn[(size_t)bq * 64 + k] = e / sum;
}

// ---------------- Kernel C: out = attn * V ----------------
// lane = q; each wave owns 64 consecutive rows. The V-row address is
// wave-uniform -> uniform/scalar loads (no LDS, no barriers). attn row for
// q=l lives in 64 VGPRs; 4-way-split accumulator breaks the fp32 dep chain.
__global__ __launch_bounds__(256) void out_kernel(
    const float* __restrict__ V, const float* __restrict__ attn,
    float* __restrict__ out) {
  const int blk = blockIdx.x;           // 16 b x 64 tiles of 256 rows
  const int b = blk >> 6;
  const int tile = blk & 63;
  const int w = threadIdx.x >> 6;
  const int l = threadIdx.x & 63;       // lane = q

  // attn row for q = l into registers (64 VGPRs)
  float a[64];
  const float4* arow = (const float4*)(attn + ((size_t)b * 64 + l) * 64);
#pragma unroll
  for (int j = 0; j < 16; ++j) {
    float4 t = arow[j];
    a[4 * j]     = t.x;
    a[4 * j + 1] = t.y;
    a[4 * j + 2] = t.z;
    a[4 * j + 3] = t.w;
  }

  const int row0 = tile * 256 + w * 64;             // this wave's 64 rows
  const float4* Vg = (const float4*)(V + ((size_t)b * 16384 + row0) * 64);
  float* outg = out + ((size_t)b * 16384 + row0) * 64;

#pragma unroll 2
  for (int r = 0; r < 64; ++r) {
    const float4* vrow = Vg + r * 16;               // wave-uniform address
    float acc0 = 0.f, acc1 = 0.f, acc2 = 0.f, acc3 = 0.f;
#pragma unroll
    for (int j = 0; j < 16; j += 4) {
      float4 v0 = vrow[j];
      float4 v1 = vrow[j + 1];
      float4 v2 = vrow[j + 2];
      float4 v3 = vrow[j + 3];
      acc0 += a[4*j+ 0] * v0.x + a[4*j+ 1] * v0.y + a[4*j+ 2] * v0.z + a[4*j+ 3] * v0.w;
      acc1 += a[4*j+ 4] * v1.x + a[4*j+ 5] * v1.y + a[4*j+ 6] * v1.z + a[4*j+ 7] * v1.w;
      acc2 += a[4*j+ 8] * v2.x + a[4*j+ 9] * v2.y + a[4*j+10] * v2.z + a[4*j+11] * v2.w;
      acc3 += a[4*j+12] * v3.x + a[4*j+13] * v3.y + a[4*j+14] * v3.z + a[4*j+15] * v3.w;
    }
    outg[(size_t)r * 64 + l] = (acc0 + acc1) + (acc2 + acc3);  // coalesced 256 B
  }
}

extern "C" void kernel_launch(void* const* d_in, const int* in_sizes, int n_in,
                              void* d_out, int out_size, void* d_ws, size_t ws_size,
                              hipStream_t stream) {
  const float* Q = (const float*)d_in[0];
  const float* K = (const float*)d_in[1];
  const float* V = (const float*)d_in[2];
  float* out = (float*)d_out;

  float* partial = (float*)d_ws;                         // 16*S_SPLIT*4096 floats = 8 MB
  float* attn = partial + (size_t)16 * S_SPLIT * 4096;   // 256 KB

  scores_kernel<<<16 * S_SPLIT, 256, 0, stream>>>(Q, K, partial);
  softmax_kernel<<<16 * 64, 64, 0, stream>>>(partial, attn);
  out_kernel<<<16 * 64, 256, 0, stream>>>(V, attn, out);
}

// Round 4
// 274.499 us; speedup vs baseline: 1.7881x; 1.7881x over previous
//
#include <hip/hip_runtime.h>

// Attention over channel dim: B=16, HW=16384, C=64, fp32.
// scores[b,q,k] = sum_hw Q[b,hw,q]*K[b,hw,k]; attn=softmax_k; out[b,hw,q]=sum_k attn[b,q,k]*V[b,hw,k]
//
// ws layout: partial scores [B][S_SPLIT][64][64] fp32 (8 MB), then attn [B][64][64] fp32 (256 KB).

#define S_SPLIT 32
#define CHUNK (16384 / S_SPLIT)   // 512 rows per split block
#define TILE_ROWS 32              // rows staged in LDS per iteration
#define NTILES (CHUNK / TILE_ROWS)

// ---------------- Kernel A: partial scores (split-K GEMM, 8x8 register tile) ----------------
// 4 waves compute the SAME 64x64 (q,k) tile over disjoint row subsets (r=i*4+w);
// LDS tree reduction combines the 4 quarter-partials before one coalesced store.
__global__ __launch_bounds__(256) void scores_kernel(
    const float* __restrict__ Q, const float* __restrict__ K,
    float* __restrict__ partial) {
  const int bs = blockIdx.x;            // b * S_SPLIT + s
  const int b = bs / S_SPLIT;
  const int s = bs % S_SPLIT;
  const int tid = threadIdx.x;
  const int w = tid >> 6;               // wave id 0..3
  const int l = tid & 63;               // lane
  const int q0 = (l >> 3) * 8;          // 8 q per lane
  const int k0 = (l & 7) * 8;           // 8 k per lane

  __shared__ union {
    struct { float4 q[2][512]; float4 k[2][512]; } t;  // 2 x (8KB Q + 8KB K) = 32 KB
    float red[2][4096];                                // 32 KB reduction scratch
  } lds;

  float acc[8][8];
#pragma unroll
  for (int i = 0; i < 8; ++i)
#pragma unroll
    for (int j = 0; j < 8; ++j) acc[i][j] = 0.f;

  const char* Qg = (const char*)(Q + ((size_t)b * 16384 + (size_t)s * CHUNK) * 64);
  const char* Kg = (const char*)(K + ((size_t)b * 16384 + (size_t)s * CHUNK) * 64);

  auto stage = [&](int t, int p) {
    const char* qsrc = Qg + (size_t)t * 8192;
    const char* ksrc = Kg + (size_t)t * 8192;
    char* qdst = (char*)&lds.t.q[p][0];
    char* kdst = (char*)&lds.t.k[p][0];
#pragma unroll
    for (int c = 0; c < 2; ++c) {
      const int m = w + c * 4;          // 8 chunks of 1024 B per matrix
      __builtin_amdgcn_global_load_lds(
          (const __attribute__((address_space(1))) unsigned*)(qsrc + m * 1024 + l * 16),
          (__attribute__((address_space(3))) unsigned*)(qdst + m * 1024), 16, 0, 0);
      __builtin_amdgcn_global_load_lds(
          (const __attribute__((address_space(1))) unsigned*)(ksrc + m * 1024 + l * 16),
          (__attribute__((address_space(3))) unsigned*)(kdst + m * 1024), 16, 0, 0);
    }
  };

  stage(0, 0);
  for (int t = 0; t < NTILES; ++t) {
    __syncthreads();                    // drains tile-t loads; frees buf (t+1)&1
    if (t + 1 < NTILES) stage(t + 1, (t + 1) & 1);
    const float4* bq = lds.t.q[t & 1];
    const float4* bk = lds.t.k[t & 1];

#pragma unroll
    for (int i = 0; i < 8; ++i) {
      const int r = (i << 2) + w;       // wave w handles rows w,4+w,...,28+w
      float4 qa = bq[r * 16 + (q0 >> 2)];
      float4 qb = bq[r * 16 + (q0 >> 2) + 1];
      float4 ka = bk[r * 16 + (k0 >> 2)];
      float4 kb = bk[r * 16 + (k0 >> 2) + 1];
      float qv[8] = {qa.x, qa.y, qa.z, qa.w, qb.x, qb.y, qb.z, qb.w};
      float kv[8] = {ka.x, ka.y, ka.z, ka.w, kb.x, kb.y, kb.z, kb.w};
#pragma unroll
      for (int ii = 0; ii < 8; ++ii)
#pragma unroll
        for (int jj = 0; jj < 8; ++jj)
          acc[ii][jj] += qv[ii] * kv[jj];
    }
  }

  // ---- cross-wave reduction: waves 2,3 publish; waves 0,1 add; halves summed on store ----
  __syncthreads();
  if (w >= 2) {
    float4* dst = (float4*)lds.red[w - 2];
#pragma unroll
    for (int i = 0; i < 8; ++i) {
      dst[(q0 + i) * 16 + (k0 >> 2)]     = make_float4(acc[i][0], acc[i][1], acc[i][2], acc[i][3]);
      dst[(q0 + i) * 16 + (k0 >> 2) + 1] = make_float4(acc[i][4], acc[i][5], acc[i][6], acc[i][7]);
    }
  }
  __syncthreads();
  if (w < 2) {
    float4* dst = (float4*)lds.red[w];
#pragma unroll
    for (int i = 0; i < 8; ++i) {
      float4 u = dst[(q0 + i) * 16 + (k0 >> 2)];
      float4 v = dst[(q0 + i) * 16 + (k0 >> 2) + 1];
      dst[(q0 + i) * 16 + (k0 >> 2)]     = make_float4(u.x + acc[i][0], u.y + acc[i][1], u.z + acc[i][2], u.w + acc[i][3]);
      dst[(q0 + i) * 16 + (k0 >> 2) + 1] = make_float4(v.x + acc[i][4], v.y + acc[i][5], v.z + acc[i][6], v.w + acc[i][7]);
    }
  }
  __syncthreads();
  float4* p4 = (float4*)(partial + (size_t)bs * 4096);
  const float4* r0 = (const float4*)lds.red[0];
  const float4* r1 = (const float4*)lds.red[1];
#pragma unroll
  for (int c = 0; c < 4; ++c) {
    float4 x = r0[c * 256 + tid];
    float4 y = r1[c * 256 + tid];
    p4[c * 256 + tid] = make_float4(x.x + y.x, x.y + y.y, x.z + y.z, x.w + y.w);
  }
}

// ---------------- Kernel B: reduce partials + softmax over k ----------------
__global__ __launch_bounds__(64) void softmax_kernel(
    const float* __restrict__ partial, float* __restrict__ attn) {
  const int bq = blockIdx.x;            // b*64 + q
  const int b = bq >> 6;
  const int q = bq & 63;
  const int k = threadIdx.x;            // lane = k

  float v = 0.f;
  for (int s = 0; s < S_SPLIT; ++s)
    v += partial[((size_t)(b * S_SPLIT + s) * 64 + q) * 64 + k];

  float m = v;
#pragma unroll
  for (int off = 32; off > 0; off >>= 1)
    m = fmaxf(m, __shfl_xor(m, off, 64));
  float e = __expf(v - m);
  float sum = e;
#pragma unroll
  for (int off = 32; off > 0; off >>= 1)
    sum += __shfl_xor(sum, off, 64);
  attn[(size_t)bq * 64 + k] = e / sum;
}

// ---------------- Kernel C: out = attn * V (8x8 register tile, dot-product form) ----------------
// Lane owns 8 consecutive rows (8*(l&7)+i within its wave's 64-row subtile) and
// 8 interleaved q (q=8j+(l>>3)). Per 4-k chunk: 8 global b128 V-loads (each V
// element read exactly once per block) + 8 conflict-free LDS b128 A-loads
// (attn rows padded to 68 floats: bank start = 4*(l>>3), tiles all 32 banks)
// feed 256 FMAs. No barriers in the main loop.
__global__ __launch_bounds__(256) void out_kernel(
    const float* __restrict__ V, const float* __restrict__ attn,
    float* __restrict__ out) {
  const int blk = blockIdx.x;           // 16 b x 64 tiles of 256 rows
  const int b = blk >> 6;
  const int tile = blk & 63;
  const int tid = threadIdx.x;
  const int w = tid >> 6;
  const int l = tid & 63;

  __shared__ float As[64 * 68];         // attn[b] rows padded 64->68 floats (17.4 KB)

  // cooperative load of attn[b] (16 KB) into padded LDS
  const float4* ag = (const float4*)(attn + (size_t)b * 4096);
#pragma unroll
  for (int m = 0; m < 4; ++m) {
    const int f = m * 256 + tid;        // float4 index 0..1023
    const int r = f >> 4, c4 = f & 15;
    *(float4*)(&As[r * 68 + c4 * 4]) = ag[f];
  }
  __syncthreads();

  const int rowbase = tile * 256 + w * 64 + (l & 7) * 8;  // lane's 8 consecutive rows
  const int qbase = l >> 3;                               // q_j = 8*j + qbase
  const float4* Vg = (const float4*)(V + ((size_t)b * 16384 + rowbase) * 64);

  float acc[8][8] = {};

#pragma unroll 2
  for (int kc = 0; kc < 16; ++kc) {     // 4 k per step
    float4 a[8], v[8];
#pragma unroll
    for (int j = 0; j < 8; ++j)
      a[j] = *(const float4*)(&As[(8 * j + qbase) * 68 + kc * 4]);
#pragma unroll
    for (int i = 0; i < 8; ++i)
      v[i] = Vg[i * 16 + kc];           // row i, k chunk kc
#pragma unroll
    for (int i = 0; i < 8; ++i)
#pragma unroll
      for (int j = 0; j < 8; ++j)
        acc[i][j] += v[i].x * a[j].x + v[i].y * a[j].y + v[i].z * a[j].z + v[i].w * a[j].w;
  }

  float* og = out + ((size_t)b * 16384 + rowbase) * 64 + qbase;
#pragma unroll
  for (int i = 0; i < 8; ++i)
#pragma unroll
    for (int j = 0; j < 8; ++j)
      og[(size_t)i * 64 + 8 * j] = acc[i][j];  // exact-once scattered b32 stores
}

extern "C" void kernel_launch(void* const* d_in, const int* in_sizes, int n_in,
                              void* d_out, int out_size, void* d_ws, size_t ws_size,
                              hipStream_t stream) {
  const float* Q = (const float*)d_in[0];
  const float* K = (const float*)d_in[1];
  const float* V = (const float*)d_in[2];
  float* out = (float*)d_out;

  float* partial = (float*)d_ws;                         // 16*S_SPLIT*4096 floats = 8 MB
  float* attn = partial + (size_t)16 * S_SPLIT * 4096;   // 256 KB

  scores_kernel<<<16 * S_SPLIT, 256, 0, stream>>>(Q, K, partial);
  softmax_kernel<<<16 * 64, 64, 0, stream>>>(partial, attn);
  out_kernel<<<16 * 64, 256, 0, stream>>>(V, attn, out);
}